// Round 3
// baseline (73.926 us; speedup 1.0000x reference)
//
#include <hip/hip_runtime.h>

#define NTOK 16384   // B*T = 4*4096
#define BQ 4
#define TQ 4096
#define SQ 8192
#define BLK 1024
#define PER_T 16
#define NSLOT 32
#define HPAD 33      // hist[bin][slot]: bank=(bin+slot)%32 -> conflict-free in-wave

__device__ __forceinline__ unsigned score_key(float s) {
    unsigned u = __float_as_uint(s);
    if ((u << 1) == 0u) u = 0u;                 // -0.0 == +0.0
    return (u & 0x80000000u) ? ~u : (u | 0x80000000u);
}

// K1: block 0 = exact stable top-K -> 16384-bit selection mask in ws.
//     blocks 1..8 = copy non-window halves of bids -> out1 (overlapped).
__global__ __launch_bounds__(BLK) void select_kernel(
    const float* __restrict__ scores,
    const int* __restrict__ bids,
    const int* __restrict__ kptr,
    unsigned long long* __restrict__ bm,
    int* __restrict__ out1)
{
    const int tid = threadIdx.x;

    if (blockIdx.x > 0) {
        int g  = (blockIdx.x - 1) * BLK + tid;      // [0, 8192) int4 units
        int o4 = g << 2;                            // int offset in [0, 32768)
        int c  = o4 >> 12;                          // chunk 0..7 (4096 ints each)
        int b  = c & 3, plane = c >> 2;
        int off = o4 & 4095;
        int addr = (plane == 0) ? (b * SQ + off)
                                : (BQ * SQ + b * SQ + TQ + off);
        *(int4*)(out1 + addr) = *(const int4*)(bids + addr);
        return;
    }

    __shared__ int hist[256][HPAD];   // ~33 KB
    __shared__ int cnt[256];
    __shared__ int scanbuf[BLK];
    __shared__ unsigned s_prefix;
    __shared__ int s_krem, s_E;

    const int K = kptr[0];
    const bool none = (K <= 0);
    const bool all  = (K >= NTOK);
    const bool run  = !none && !all;
    const int slot = tid & (NSLOT - 1);

    for (int t = tid; t < 256 * HPAD; t += BLK) ((int*)hist)[t] = 0;
    if (tid == 0) { s_prefix = 0u; s_krem = K; s_E = K; }
    __syncthreads();

    unsigned key[PER_T];
    #pragma unroll
    for (int t = 0; t < PER_T; ++t) {
        unsigned k = score_key(scores[t * BLK + tid]);
        key[t] = k;
        if (run) atomicAdd(&hist[k >> 24][slot], 1);
    }
    __syncthreads();

    for (int level = 0; level < 4; ++level) {
        if (tid < 256) {
            int s = 0;
            #pragma unroll
            for (int j = 0; j < NSLOT; ++j) s += hist[tid][j];
            cnt[tid] = s;
        }
        __syncthreads();

        if (run && tid < 64) {
            int c0 = cnt[4 * tid], c1 = cnt[4 * tid + 1];
            int c2 = cnt[4 * tid + 2], c3 = cnt[4 * tid + 3];
            int T = c0 + c1 + c2 + c3;
            int incl = T;
            #pragma unroll
            for (int off = 1; off < 64; off <<= 1) {
                int o = __shfl_down(incl, off, 64);
                if (tid + off < 64) incl += o;
            }
            int suf4 = incl - T;
            int suf3 = suf4 + c3;
            int suf2 = suf3 + c2;
            int suf1 = suf2 + c1;
            int suf0 = suf1 + c0;
            int krem = s_krem;
            int shift = 24 - 8 * level;
            int sufs[5] = {suf0, suf1, suf2, suf3, suf4};
            int cs[4] = {c0, c1, c2, c3};
            #pragma unroll
            for (int j = 0; j < 4; ++j) {
                if (sufs[j] >= krem && sufs[j + 1] < krem) {
                    s_prefix = s_prefix | ((unsigned)(4 * tid + j) << shift);
                    s_krem = krem - sufs[j + 1];
                    s_E = cs[j];
                }
            }
        }
        __syncthreads();

        if (level < 3) {
            for (int t = tid; t < 256 * HPAD; t += BLK) ((int*)hist)[t] = 0;
            __syncthreads();
            if (run) {
                unsigned pref = s_prefix;
                int msh = 24 - 8 * level;
                int shift = msh - 8;
                #pragma unroll
                for (int t = 0; t < PER_T; ++t) {
                    unsigned k = key[t];
                    if ((k >> msh) == (pref >> msh))
                        atomicAdd(&hist[(k >> shift) & 255][slot], 1);
                }
            }
            __syncthreads();
        }
    }

    const unsigned Tstar = s_prefix;
    const int R = s_krem, E = s_E;

    if (!run || R == E) {
        // Fast path: sel = key >= Tstar. Emit bitmask via ballot.
        #pragma unroll
        for (int t = 0; t < PER_T; ++t) {
            bool sel = none ? false : (all ? true : (key[t] >= Tstar));
            unsigned long long m = __ballot(sel);
            if ((tid & 63) == 0) bm[t * 16 + (tid >> 6)] = m;
        }
    } else {
        // Rare path (boundary tie): stable index-order tie-break, chunked layout.
        unsigned ck[PER_T];
        int cntEq = 0;
        #pragma unroll
        for (int j = 0; j < PER_T; ++j) {
            unsigned k = score_key(scores[tid * PER_T + j]);
            ck[j] = k;
            cntEq += (k == Tstar) ? 1 : 0;
        }
        scanbuf[tid] = cntEq;
        __syncthreads();
        for (int off = 1; off < BLK; off <<= 1) {
            int v = scanbuf[tid];
            int add = (tid >= off) ? scanbuf[tid - off] : 0;
            __syncthreads();
            scanbuf[tid] = v + add;
            __syncthreads();
        }
        int running = scanbuf[tid] - cntEq;
        unsigned mask16 = 0;
        for (int j = 0; j < PER_T; ++j) {
            unsigned k = ck[j];
            bool sel;
            if (k > Tstar) sel = true;
            else if (k == Tstar) { sel = (running < R); ++running; }
            else sel = false;
            if (sel) mask16 |= (1u << j);
        }
        __syncthreads();
        scanbuf[tid] = (int)mask16;
        __syncthreads();
        if (tid < 256) {
            unsigned long long W = 0;
            #pragma unroll
            for (int j = 0; j < 4; ++j)
                W |= ((unsigned long long)((unsigned)scanbuf[4 * tid + j] & 0xFFFFu)) << (16 * j);
            bm[tid] = W;
        }
    }
}

// K2: apply mux + fan out to out0 and both out1 windows (int4, 16 CUs).
__global__ __launch_bounds__(256) void epilogue_kernel(
    const int* __restrict__ cand,
    const int* __restrict__ tok,
    const unsigned long long* __restrict__ bm,
    int* __restrict__ out0,
    int* __restrict__ out1)
{
    int q = blockIdx.x * 256 + threadIdx.x;   // [0, 4096) int4 units
    int i = q << 2;
    unsigned bits = (unsigned)(bm[i >> 6] >> (i & 60)) & 0xFu;
    int4 c = ((const int4*)cand)[q];
    int4 t = ((const int4*)tok)[q];
    int4 v;
    v.x = (bits & 1u) ? c.x : t.x;
    v.y = (bits & 2u) ? c.y : t.y;
    v.z = (bits & 4u) ? c.z : t.z;
    v.w = (bits & 8u) ? c.w : t.w;
    ((int4*)out0)[q] = v;
    int b = i >> 12, tt = i & 4095;
    *(int4*)(out1 + b * SQ + (SQ - TQ) + tt) = v;   // plane 0 window
    *(int4*)(out1 + BQ * SQ + b * SQ + tt) = v;     // plane 1 window
}

extern "C" void kernel_launch(void* const* d_in, const int* in_sizes, int n_in,
                              void* d_out, int out_size, void* d_ws, size_t ws_size,
                              hipStream_t stream) {
    const int*   tok    = (const int*)d_in[0];   // tokens          [4,4096]
    const int*   bids   = (const int*)d_in[1];   // batch_input_ids [2,4,8192]
    const int*   cand   = (const int*)d_in[2];   // candidate_tokens[4,4096]
    const float* scores = (const float*)d_in[3]; // candidate_scores[4,4096]
    const int*   kptr   = (const int*)d_in[4];   // unmask_count scalar

    int* out0 = (int*)d_out;        // updated_tokens, 16384 ints
    int* out1 = out0 + NTOK;        // upd, 65536 ints
    unsigned long long* bm = (unsigned long long*)d_ws;  // 256 x u64 = 2 KB

    select_kernel<<<9, BLK, 0, stream>>>(scores, bids, kptr, bm, out1);
    epilogue_kernel<<<NTOK / 4 / 256, 256, 0, stream>>>(cand, tok, bm, out0, out1);
}

// Round 4
// 70.833 us; speedup vs baseline: 1.0437x; 1.0437x over previous
//
#include <hip/hip_runtime.h>

#define NTOK 16384   // B*T = 4*4096
#define BQ 4
#define TQ 4096
#define SQ 8192
#define BLK 1024
#define PER_T 16
#define NSLOT 32
#define HPAD 33      // hist[bin][slot]: bank=(bin+slot)%32 -> conflict-free in-wave
#define NBLOCKS 17   // block 0 = select; 1..8 also copy; 1..16 do epilogue

__device__ __forceinline__ unsigned score_key(float s) {
    unsigned u = __float_as_uint(s);
    if ((u << 1) == 0u) u = 0u;                 // -0.0 == +0.0
    return (u & 0x80000000u) ? ~u : (u | 0x80000000u);
}

__global__ __launch_bounds__(BLK) void token_update_kernel(
    const float* __restrict__ scores,
    const int* __restrict__ cand,
    const int* __restrict__ tok,
    const int* __restrict__ bids,
    const int* __restrict__ kptr,
    int* __restrict__ out0,
    int* __restrict__ out1,
    unsigned long long* __restrict__ bm)   // ws: 256 x u64 bitmask + u32 flag
{
    const int tid = threadIdx.x;
    const int bid = blockIdx.x;
    unsigned* flag = (unsigned*)(bm + 256);

    if (bid > 0) {
        // ---- copy non-window halves of bids -> out1, overlapped with select ----
        if (bid <= 8) {
            int g  = (bid - 1) * BLK + tid;         // [0, 8192) int4 units
            int o4 = g << 2;                        // int offset in [0, 32768)
            int c  = o4 >> 12;                      // chunk 0..7 (4096 ints)
            int b  = c & 3, plane = c >> 2;
            int off = o4 & 4095;
            int addr = (plane == 0) ? (b * SQ + off)
                                    : (BQ * SQ + b * SQ + TQ + off);
            *(int4*)(out1 + addr) = *(const int4*)(bids + addr);
        }
        // ---- wait for block 0 to publish the selection bitmask ----
        while (__hip_atomic_load(flag, __ATOMIC_ACQUIRE, __HIP_MEMORY_SCOPE_AGENT) != 1u)
            __builtin_amdgcn_s_sleep(1);
        // ---- epilogue: mux + fan-out, 256 int4 per block across 16 CUs ----
        if (tid < 256) {
            int q = (bid - 1) * 256 + tid;          // [0, 4096) int4 units
            int i = q << 2;
            unsigned bits = (unsigned)(bm[q >> 4] >> ((q & 15) * 4)) & 0xFu;
            int4 c4 = ((const int4*)cand)[q];
            int4 t4 = ((const int4*)tok)[q];
            int4 v;
            v.x = (bits & 1u) ? c4.x : t4.x;
            v.y = (bits & 2u) ? c4.y : t4.y;
            v.z = (bits & 4u) ? c4.z : t4.z;
            v.w = (bits & 8u) ? c4.w : t4.w;
            ((int4*)out0)[q] = v;
            int b = i >> 12, tt = i & 4095;
            *(int4*)(out1 + b * SQ + (SQ - TQ) + tt) = v;   // plane 0 window
            *(int4*)(out1 + BQ * SQ + b * SQ + tt) = v;     // plane 1 window
        }
        return;
    }

    // ---- Block 0: exact stable top-K (radix refine, chunked keys) ----
    __shared__ int hist[256][HPAD];   // ~33 KB
    __shared__ int cnt[256];
    __shared__ int scanbuf[BLK];
    __shared__ unsigned s_prefix;
    __shared__ int s_krem, s_E;

    const int K = kptr[0];
    const bool none = (K <= 0);
    const bool all  = (K >= NTOK);
    const bool run  = !none && !all;
    const int slot = tid & (NSLOT - 1);

    for (int t = tid; t < 256 * HPAD; t += BLK) ((int*)hist)[t] = 0;
    if (tid == 0) { s_prefix = 0u; s_krem = K; s_E = K; }
    __syncthreads();

    // Load 16 contiguous keys per thread via 4 float4 loads (i = 16*tid + j).
    unsigned key[PER_T];
    const float4* s4v = (const float4*)scores;
    #pragma unroll
    for (int c = 0; c < 4; ++c) {
        float4 f = s4v[tid * 4 + c];
        key[4 * c + 0] = score_key(f.x);
        key[4 * c + 1] = score_key(f.y);
        key[4 * c + 2] = score_key(f.z);
        key[4 * c + 3] = score_key(f.w);
    }
    if (run) {
        #pragma unroll
        for (int j = 0; j < PER_T; ++j) atomicAdd(&hist[key[j] >> 24][slot], 1);
    }
    __syncthreads();

    if (run) {
        for (int level = 0; level < 4; ++level) {
            // Reduce 32 slots -> cnt[bin], zero hist in the same pass.
            if (tid < 256) {
                int s = 0;
                #pragma unroll
                for (int j = 0; j < NSLOT; ++j) { s += hist[tid][j]; hist[tid][j] = 0; }
                cnt[tid] = s;
            }
            __syncthreads();

            // Wave 0: suffix scan over 256 bins + boundary find (barrier-free).
            if (tid < 64) {
                int c0 = cnt[4 * tid], c1 = cnt[4 * tid + 1];
                int c2 = cnt[4 * tid + 2], c3 = cnt[4 * tid + 3];
                int T = c0 + c1 + c2 + c3;
                int incl = T;
                #pragma unroll
                for (int off = 1; off < 64; off <<= 1) {
                    int o = __shfl_down(incl, off, 64);
                    if (tid + off < 64) incl += o;
                }
                int suf4 = incl - T;
                int suf3 = suf4 + c3;
                int suf2 = suf3 + c2;
                int suf1 = suf2 + c1;
                int suf0 = suf1 + c0;
                int krem = s_krem;
                int shift = 24 - 8 * level;
                int sufs[5] = {suf0, suf1, suf2, suf3, suf4};
                int cs[4] = {c0, c1, c2, c3};
                #pragma unroll
                for (int j = 0; j < 4; ++j) {
                    if (sufs[j] >= krem && sufs[j + 1] < krem) {
                        s_prefix = s_prefix | ((unsigned)(4 * tid + j) << shift);
                        s_krem = krem - sufs[j + 1];
                        s_E = cs[j];
                    }
                }
            }
            __syncthreads();

            // Early exit: boundary bin fully selected -> sel == (key >= prefix<<shift).
            if (s_krem == s_E) break;

            if (level < 3) {
                unsigned pref = s_prefix;
                int msh = 24 - 8 * level;
                int shift = msh - 8;
                #pragma unroll
                for (int j = 0; j < PER_T; ++j) {
                    unsigned k = key[j];
                    if ((k >> msh) == (pref >> msh))
                        atomicAdd(&hist[(k >> shift) & 255][slot], 1);
                }
                __syncthreads();
            }
        }
    }

    const unsigned Tstar = s_prefix;
    const int R = s_krem, E = s_E;
    unsigned mask16 = 0;

    if (!run || R == E) {
        // Fast path: sel = key >= Tstar (low bits of Tstar are 0 on early exit).
        #pragma unroll
        for (int j = 0; j < PER_T; ++j) {
            bool sel = none ? false : (all ? true : (key[j] >= Tstar));
            mask16 |= sel ? (1u << j) : 0u;
        }
    } else {
        // Rare path (boundary tie, R < E): stable index-order tie-break.
        int cntEq = 0;
        #pragma unroll
        for (int j = 0; j < PER_T; ++j) cntEq += (key[j] == Tstar) ? 1 : 0;
        scanbuf[tid] = cntEq;
        __syncthreads();
        for (int off = 1; off < BLK; off <<= 1) {
            int v = scanbuf[tid];
            int add = (tid >= off) ? scanbuf[tid - off] : 0;
            __syncthreads();
            scanbuf[tid] = v + add;
            __syncthreads();
        }
        int running = scanbuf[tid] - cntEq;   // equals before my chunk
        for (int j = 0; j < PER_T; ++j) {
            unsigned k = key[j];
            bool sel;
            if (k > Tstar) sel = true;
            else if (k == Tstar) { sel = (running < R); ++running; }
            else sel = false;
            mask16 |= sel ? (1u << j) : 0u;
        }
        __syncthreads();   // scanbuf reused below
    }

    // Assemble 16384-bit mask: bm[w] bit b <-> global index 64*w + b.
    scanbuf[tid] = (int)mask16;
    __syncthreads();
    if (tid < 256) {
        unsigned long long W = 0;
        #pragma unroll
        for (int j = 0; j < 4; ++j)
            W |= ((unsigned long long)((unsigned)scanbuf[4 * tid + j] & 0xFFFFu)) << (16 * j);
        bm[tid] = W;
    }
    __syncthreads();
    if (tid == 0)
        __hip_atomic_store(flag, 1u, __ATOMIC_RELEASE, __HIP_MEMORY_SCOPE_AGENT);
}

extern "C" void kernel_launch(void* const* d_in, const int* in_sizes, int n_in,
                              void* d_out, int out_size, void* d_ws, size_t ws_size,
                              hipStream_t stream) {
    const int*   tok    = (const int*)d_in[0];   // tokens          [4,4096]
    const int*   bids   = (const int*)d_in[1];   // batch_input_ids [2,4,8192]
    const int*   cand   = (const int*)d_in[2];   // candidate_tokens[4,4096]
    const float* scores = (const float*)d_in[3]; // candidate_scores[4,4096]
    const int*   kptr   = (const int*)d_in[4];   // unmask_count scalar

    int* out0 = (int*)d_out;        // updated_tokens, 16384 ints
    int* out1 = out0 + NTOK;        // upd, 65536 ints
    unsigned long long* bm = (unsigned long long*)d_ws;  // 2 KB + flag

    token_update_kernel<<<NBLOCKS, BLK, 0, stream>>>(
        scores, cand, tok, bids, kptr, out0, out1, bm);
}

// Round 5
// 66.743 us; speedup vs baseline: 1.1076x; 1.0613x over previous
//
#include <hip/hip_runtime.h>

#define NTOK 16384   // B*T = 4*4096
#define BQ 4
#define TQ 4096
#define SQ 8192
#define BLK 1024
#define NBLK 16

__device__ __forceinline__ unsigned score_key(float s) {
    unsigned u = __float_as_uint(s);
    if ((u << 1) == 0u) u = 0u;                 // -0.0 == +0.0
    return (u & 0x80000000u) ? ~u : (u | 0x80000000u);
}

// Every block redundantly computes the exact top-K threshold over packed
// P = (key << 14) | (16383 - idx)  (all distinct -> no tie-break phase),
// then writes its own 1/16 output slice. Zero inter-block synchronization.
__global__ __launch_bounds__(BLK) void token_update_kernel(
    const float* __restrict__ scores,
    const int* __restrict__ cand,
    const int* __restrict__ tok,
    const int* __restrict__ bids,
    const int* __restrict__ kptr,
    int* __restrict__ out0,
    int* __restrict__ out1)
{
    __shared__ int h0[2048 * 4];      // 32 KB: level-0 hist, 4 slots per bin
    __shared__ int h1[128];           // refinement hist (7 bits/level)
    __shared__ int wtot[16], wsuf[16];
    __shared__ unsigned long long s_pref;
    __shared__ int s_krem, s_E;

    const int tid  = threadIdx.x;
    const int B    = blockIdx.x;
    const int lane = tid & 63;
    const int w    = tid >> 6;

    // ---- bids non-window copy (independent; issue first to overlap) ----
    if (tid < 512) {
        int g   = B * 512 + tid;              // [0, 8192) int4 units
        int o4  = g << 2;                     // int offset in [0, 32768)
        int c   = o4 >> 12;                   // chunk 0..7 (4096 ints)
        int b   = c & 3, plane = c >> 2;
        int off = o4 & 4095;
        int addr = plane ? (BQ * SQ + b * SQ + TQ + off) : (b * SQ + off);
        *(int4*)(out1 + addr) = *(const int4*)(bids + addr);
    }

    const int K = kptr[0];
    const bool none = (K <= 0), all = (K >= NTOK);
    const bool run  = !none && !all;          // uniform across block

    for (int t = tid; t < 2048 * 4; t += BLK) h0[t] = 0;
    if (tid == 0) { s_pref = 0ull; s_krem = 1; s_E = 1; }
    __syncthreads();

    // ---- load ALL 16384 keys (16/thread, float4 coalesced) + level-0 hist ----
    unsigned key[16];
    const float4* s4 = (const float4*)scores;
    #pragma unroll
    for (int c = 0; c < 4; ++c) {
        float4 f = s4[c * BLK + tid];
        key[c * 4 + 0] = score_key(f.x);
        key[c * 4 + 1] = score_key(f.y);
        key[c * 4 + 2] = score_key(f.z);
        key[c * 4 + 3] = score_key(f.w);
    }
    unsigned long long pref = 0ull;
    int rbits = 35;

    if (run) {
        const int slot = tid & 3;
        #pragma unroll
        for (int j = 0; j < 16; ++j)
            atomicAdd(&h0[(key[j] >> 21) * 4 + slot], 1);
        __syncthreads();

        // ---- level 0: reduce slots, block-wide suffix scan over 2048 bins ----
        int4 pa = *(int4*)&h0[8 * tid];
        int4 pb = *(int4*)&h0[8 * tid + 4];
        int c0 = pa.x + pa.y + pa.z + pa.w;    // bin 2*tid
        int c1 = pb.x + pb.y + pb.z + pb.w;    // bin 2*tid+1
        int pairSum = c0 + c1;
        int incl = pairSum;
        #pragma unroll
        for (int off = 1; off < 64; off <<= 1) {
            int o = __shfl_down(incl, off, 64);
            if (lane + off < 64) incl += o;
        }
        if (lane == 0) wtot[w] = incl;
        __syncthreads();
        if (tid < 16) {
            int v = wtot[tid];
            int i2 = v;
            #pragma unroll
            for (int off = 1; off < 16; off <<= 1) {
                int o = __shfl_down(i2, off, 64);
                if (tid + off < 16) i2 += o;
            }
            wsuf[tid] = i2 - v;                // sum of waves strictly after
        }
        __syncthreads();
        int sufPairAfter = (incl - pairSum) + wsuf[w];
        int suf1 = sufPairAfter;               // suffix after bin 2t+1
        int incl1 = suf1 + c1;
        int suf0 = incl1;                      // suffix after bin 2t
        int incl0 = suf0 + c0;
        if (incl1 >= K && suf1 < K) { s_pref = (unsigned long long)(2 * tid + 1); s_krem = K - suf1; s_E = c1; }
        if (incl0 >= K && suf0 < K) { s_pref = (unsigned long long)(2 * tid + 0); s_krem = K - suf0; s_E = c0; }
        __syncthreads();

        pref = s_pref;
        int krem = s_krem, E = s_E;

        // ---- refinement: 7 bits/level on register-held keys, early exit ----
        for (int L = 1; L <= 5 && krem != E; ++L) {
            int sh = 35 - 7 * L;
            if (tid < 128) h1[tid] = 0;
            __syncthreads();
            #pragma unroll
            for (int j = 0; j < 16; ++j) {
                int i = (((j >> 2) * BLK + tid) << 2) | (j & 3);
                unsigned long long P = ((unsigned long long)key[j] << 14)
                                     | (unsigned)(NTOK - 1 - i);
                if ((P >> (sh + 7)) == pref)
                    atomicAdd(&h1[(int)((P >> sh) & 127)], 1);
            }
            __syncthreads();
            if (tid < 64) {
                int d0 = h1[2 * tid], d1 = h1[2 * tid + 1];
                int T = d0 + d1;
                int inc = T;
                #pragma unroll
                for (int off = 1; off < 64; off <<= 1) {
                    int o = __shfl_down(inc, off, 64);
                    if (tid + off < 64) inc += o;
                }
                int t1 = inc - T;              // suffix after bin 2t+1
                int n1 = t1 + d1;
                int t0 = n1;                   // suffix after bin 2t
                int n0 = t0 + d0;
                if (n1 >= krem && t1 < krem) { s_pref = (pref << 7) | (unsigned)(2 * tid + 1); s_krem = krem - t1; s_E = d1; }
                if (n0 >= krem && t0 < krem) { s_pref = (pref << 7) | (unsigned)(2 * tid + 0); s_krem = krem - t0; s_E = d0; }
            }
            __syncthreads();
            pref = s_pref; krem = s_krem; E = s_E;
            rbits = sh;
        }
    }

    const unsigned long long Tstar =
        none ? ~0ull : (all ? 0ull : (pref << rbits));

    // ---- output: block B writes its 1/16 slice of out0 + both out1 windows ----
    if (tid < 256) {
        int i4 = B * 256 + tid;                // [0, 4096) int4 units
        int i  = i4 << 2;
        float4 f = s4[i4];                     // L2-hot reload
        int4 c4 = ((const int4*)cand)[i4];
        int4 t4 = ((const int4*)tok)[i4];
        unsigned k0 = score_key(f.x), k1 = score_key(f.y);
        unsigned k2 = score_key(f.z), k3 = score_key(f.w);
        unsigned long long P0 = ((unsigned long long)k0 << 14) | (unsigned)(NTOK - 1 - (i + 0));
        unsigned long long P1 = ((unsigned long long)k1 << 14) | (unsigned)(NTOK - 1 - (i + 1));
        unsigned long long P2 = ((unsigned long long)k2 << 14) | (unsigned)(NTOK - 1 - (i + 2));
        unsigned long long P3 = ((unsigned long long)k3 << 14) | (unsigned)(NTOK - 1 - (i + 3));
        int4 v;
        v.x = (P0 >= Tstar) ? c4.x : t4.x;
        v.y = (P1 >= Tstar) ? c4.y : t4.y;
        v.z = (P2 >= Tstar) ? c4.z : t4.z;
        v.w = (P3 >= Tstar) ? c4.w : t4.w;
        ((int4*)out0)[i4] = v;
        int b = i >> 12, tt = i & 4095;
        *(int4*)(out1 + b * SQ + (SQ - TQ) + tt) = v;   // plane 0 window
        *(int4*)(out1 + BQ * SQ + b * SQ + tt) = v;     // plane 1 window
    }
}

extern "C" void kernel_launch(void* const* d_in, const int* in_sizes, int n_in,
                              void* d_out, int out_size, void* d_ws, size_t ws_size,
                              hipStream_t stream) {
    const int*   tok    = (const int*)d_in[0];   // tokens          [4,4096]
    const int*   bids   = (const int*)d_in[1];   // batch_input_ids [2,4,8192]
    const int*   cand   = (const int*)d_in[2];   // candidate_tokens[4,4096]
    const float* scores = (const float*)d_in[3]; // candidate_scores[4,4096]
    const int*   kptr   = (const int*)d_in[4];   // unmask_count scalar

    int* out0 = (int*)d_out;        // updated_tokens, 16384 ints
    int* out1 = out0 + NTOK;        // upd, 65536 ints

    token_update_kernel<<<NBLK, BLK, 0, stream>>>(
        scores, cand, tok, bids, kptr, out0, out1);
}

// Round 6
// 65.808 us; speedup vs baseline: 1.1234x; 1.0142x over previous
//
#include <hip/hip_runtime.h>

#define NTOK 16384   // B*T = 4*4096
#define BQ 4
#define TQ 4096
#define SQ 8192
#define BLK 1024
#define NBLK 16

__device__ __forceinline__ unsigned score_key(float s) {
    unsigned u = __float_as_uint(s);
    if ((u << 1) == 0u) u = 0u;                 // -0.0 == +0.0
    return (u & 0x80000000u) ? ~u : (u | 0x80000000u);
}

// Every block redundantly computes the exact top-K threshold over packed
// P = (key << 14) | (16383 - idx)  (all distinct -> no tie-break phase),
// then writes its own 1/16 output slice. Zero inter-block synchronization.
__global__ __launch_bounds__(BLK) void token_update_kernel(
    const float* __restrict__ scores,
    const int* __restrict__ cand,
    const int* __restrict__ tok,
    const int* __restrict__ bids,
    const int* __restrict__ kptr,
    int* __restrict__ out0,
    int* __restrict__ out1)
{
    __shared__ int h0[2048 * 8];      // 64 KB: level-0 hist, 8 slots/bin
    __shared__ int h1[2048];          // 8 KB: refinement hist (11 bits/level)
    __shared__ int wtot[16], wsuf[16];
    __shared__ unsigned long long s_pref;
    __shared__ int s_krem, s_E;

    const int tid  = threadIdx.x;
    const int B    = blockIdx.x;
    const int lane = tid & 63;
    const int w    = tid >> 6;

    // ---- bids non-window copy (independent; issue first to overlap) ----
    if (tid < 512) {
        int g   = B * 512 + tid;              // [0, 8192) int4 units
        int o4  = g << 2;
        int c   = o4 >> 12;                   // chunk 0..7 (4096 ints)
        int b   = c & 3, plane = c >> 2;
        int off = o4 & 4095;
        int addr = plane ? (BQ * SQ + b * SQ + TQ + off) : (b * SQ + off);
        *(int4*)(out1 + addr) = *(const int4*)(bids + addr);
    }

    const int K = kptr[0];
    const bool none = (K <= 0), all = (K >= NTOK);
    const bool run  = !none && !all;          // uniform across block

    #pragma unroll
    for (int r = 0; r < 4; ++r)
        *(int4*)&h0[(r * BLK + tid) * 4] = make_int4(0, 0, 0, 0);
    if (tid == 0) { s_pref = 0ull; s_krem = 1; s_E = 1; }
    __syncthreads();

    // ---- load ALL 16384 keys (16/thread, float4 coalesced) + level-0 hist ----
    unsigned key[16];
    const float4* s4 = (const float4*)scores;
    #pragma unroll
    for (int c = 0; c < 4; ++c) {
        float4 f = s4[c * BLK + tid];
        key[c * 4 + 0] = score_key(f.x);
        key[c * 4 + 1] = score_key(f.y);
        key[c * 4 + 2] = score_key(f.z);
        key[c * 4 + 3] = score_key(f.w);
    }

    unsigned long long pref = 0ull;
    int rb = 35;

    if (run) {
        const int slot = tid & 7;
        #pragma unroll
        for (int j = 0; j < 16; ++j)
            atomicAdd(&h0[(key[j] >> 21) * 8 + slot], 1);
        __syncthreads();

        const int SH[5]   = {35, 24, 13, 2, 0};
        const int BITS[5] = {11, 11, 11, 11, 2};
        int krem = K, E = 0;

        for (int L = 0; L < 5; ++L) {
            const int sh = SH[L], bits = BITS[L];
            // counts for bins 2*tid, 2*tid+1
            int c0, c1;
            if (L == 0) {
                int4 a0 = *(int4*)&h0[tid * 16];
                int4 a1 = *(int4*)&h0[tid * 16 + 4];
                int4 b0 = *(int4*)&h0[tid * 16 + 8];
                int4 b1 = *(int4*)&h0[tid * 16 + 12];
                c0 = a0.x + a0.y + a0.z + a0.w + a1.x + a1.y + a1.z + a1.w;
                c1 = b0.x + b0.y + b0.z + b0.w + b1.x + b1.y + b1.z + b1.w;
            } else {
                c0 = h1[2 * tid]; c1 = h1[2 * tid + 1];
            }
            // block-wide suffix scan over 2048 bins (wave shuffles + 16-entry pass)
            int pairSum = c0 + c1, incl = pairSum;
            #pragma unroll
            for (int off = 1; off < 64; off <<= 1) {
                int o = __shfl_down(incl, off, 64);
                if (lane + off < 64) incl += o;
            }
            if (lane == 0) wtot[w] = incl;
            __syncthreads();
            if (tid < 16) {
                int v = wtot[tid], i2 = v;
                #pragma unroll
                for (int off = 1; off < 16; off <<= 1) {
                    int o = __shfl_down(i2, off, 64);
                    if (tid + off < 16) i2 += o;
                }
                wsuf[tid] = i2 - v;            // sum of waves strictly after
            }
            __syncthreads();
            int sufPair = (incl - pairSum) + wsuf[w];
            int suf1 = sufPair,  n1 = suf1 + c1;   // bin 2*tid+1
            int suf0 = n1,       n0 = suf0 + c0;   // bin 2*tid
            if (n1 >= krem && suf1 < krem) {
                s_pref = (pref << bits) | (unsigned)(2 * tid + 1);
                s_krem = krem - suf1; s_E = c1;
            }
            if (n0 >= krem && suf0 < krem) {
                s_pref = (pref << bits) | (unsigned)(2 * tid);
                s_krem = krem - suf0; s_E = c0;
            }
            __syncthreads();
            pref = s_pref; krem = s_krem; E = s_E; rb = sh;
            if (krem == E || L == 4) break;   // boundary bin fully selected

            // build next-level histogram over boundary-bin survivors
            h1[2 * tid] = 0; h1[2 * tid + 1] = 0;
            __syncthreads();
            const int nsh = SH[L + 1], nbits = BITS[L + 1];
            #pragma unroll
            for (int j = 0; j < 16; ++j) {
                int i = (((j >> 2) * BLK + tid) << 2) | (j & 3);
                unsigned long long P = ((unsigned long long)key[j] << 14)
                                     | (unsigned)(NTOK - 1 - i);
                if ((P >> (nsh + nbits)) == pref)
                    atomicAdd(&h1[(int)((P >> nsh) & ((1 << nbits) - 1))], 1);
            }
            __syncthreads();
        }
    }

    const unsigned long long Tstar =
        none ? ~0ull : (all ? 0ull : (pref << rb));

    // ---- output: block B writes its 1/16 slice of out0 + both out1 windows ----
    if (tid < 256) {
        int i4 = B * 256 + tid;                // [0, 4096) int4 units
        int i  = i4 << 2;
        float4 f = s4[i4];                     // L2-hot reload
        int4 c4 = ((const int4*)cand)[i4];
        int4 t4 = ((const int4*)tok)[i4];
        unsigned long long P0 = ((unsigned long long)score_key(f.x) << 14) | (unsigned)(NTOK - 1 - (i + 0));
        unsigned long long P1 = ((unsigned long long)score_key(f.y) << 14) | (unsigned)(NTOK - 1 - (i + 1));
        unsigned long long P2 = ((unsigned long long)score_key(f.z) << 14) | (unsigned)(NTOK - 1 - (i + 2));
        unsigned long long P3 = ((unsigned long long)score_key(f.w) << 14) | (unsigned)(NTOK - 1 - (i + 3));
        int4 v;
        v.x = (P0 >= Tstar) ? c4.x : t4.x;
        v.y = (P1 >= Tstar) ? c4.y : t4.y;
        v.z = (P2 >= Tstar) ? c4.z : t4.z;
        v.w = (P3 >= Tstar) ? c4.w : t4.w;
        ((int4*)out0)[i4] = v;
        int b = i >> 12, tt = i & 4095;
        *(int4*)(out1 + b * SQ + (SQ - TQ) + tt) = v;   // plane 0 window
        *(int4*)(out1 + BQ * SQ + b * SQ + tt) = v;     // plane 1 window
    }
}

extern "C" void kernel_launch(void* const* d_in, const int* in_sizes, int n_in,
                              void* d_out, int out_size, void* d_ws, size_t ws_size,
                              hipStream_t stream) {
    const int*   tok    = (const int*)d_in[0];   // tokens          [4,4096]
    const int*   bids   = (const int*)d_in[1];   // batch_input_ids [2,4,8192]
    const int*   cand   = (const int*)d_in[2];   // candidate_tokens[4,4096]
    const float* scores = (const float*)d_in[3]; // candidate_scores[4,4096]
    const int*   kptr   = (const int*)d_in[4];   // unmask_count scalar

    int* out0 = (int*)d_out;        // updated_tokens, 16384 ints
    int* out1 = out0 + NTOK;        // upd, 65536 ints

    token_update_kernel<<<NBLK, BLK, 0, stream>>>(
        scores, cand, tok, bids, kptr, out0, out1);
}